// Round 3
// baseline (685.898 us; speedup 1.0000x reference)
//
#include <hip/hip_runtime.h>
#include <stdint.h>

#define HH 512
#define WW 512
#define CIN 64
#define COUT 128
#define NB 4
#define STRIP 128
#define NCOL 130     // staged columns incl. halo
#define CPAD 72      // padded channel dim in LDS
#define YCHUNK 16

typedef __bf16 bf16x8 __attribute__((ext_vector_type(8)));
typedef __bf16 bf16x4 __attribute__((ext_vector_type(4)));
typedef float f32x4 __attribute__((ext_vector_type(4)));

__device__ __forceinline__ unsigned short f2bf(float f) {
    union { float f; uint32_t u; } v; v.f = f;
    uint32_t u = v.u;
    u += 0x7fffu + ((u >> 16) & 1u);   // RNE
    return (unsigned short)(u >> 16);
}

__global__ void zero_kernel(float4* __restrict__ p, long n4) {
    long i = (long)blockIdx.x * 256 + threadIdx.x;
    const long stride = (long)gridDim.x * 256;
    const float4 z = make_float4(0.f, 0.f, 0.f, 0.f);
    for (; i < n4; i += stride) p[i] = z;
}

// Wt2 layout: [(k>>3)][co][k&7] bf16, k = (ky*3+kx)*64 + ci  (576 x 128)
__global__ void wt_transform(const float* __restrict__ w, unsigned short* __restrict__ wt2) {
    int tid = blockIdx.x * 256 + threadIdx.x;
    if (tid >= COUT * 576) return;
    int co = tid / 576;
    int k  = tid - co * 576;
    int off = k >> 6;
    int ci  = k & 63;
    int ky = off / 3;
    int kx = off - ky * 3;
    float val = w[((co * CIN + ci) * 3 + ky) * 3 + kx];
    wt2[(size_t)(k >> 3) * (COUT * 8) + co * 8 + (k & 7)] = f2bf(val);
}

// dense ws: [B][H][W][CIN] f32 (NHWC). One lane per (point, channel).
__global__ void scatter_kernel(const float* __restrict__ feat,
                               const int* __restrict__ coors,
                               float* __restrict__ dense, int npts) {
    int t = blockIdx.x * 256 + threadIdx.x;
    int p = t >> 6;
    int c = t & 63;
    if (p >= npts) return;
    int b = coors[p * 3 + 0];
    int y = coors[p * 3 + 1];
    int x = coors[p * 3 + 2];
    atomicAdd(&dense[(((size_t)b * HH + y) * WW + x) * CIN + c], feat[(size_t)p * CIN + c]);
}

// Persistent-strip conv: block owns (batch, 128-wide x-strip, 16-row chunk),
// walks y with a 4-row LDS ring. 4 waves, each 64 sites x 64 co.
// GEMM per row: out[site][co] = sum_k patch[site][k] * Wt[k][co], K = 576.
__global__ __launch_bounds__(256, 2) void conv_kernel(
        const float* __restrict__ dense,
        const __bf16* __restrict__ wt2,
        float* __restrict__ out) {
    __shared__ __align__(16) __bf16 patch[4 * NCOL * CPAD];

    const int bid = blockIdx.x;
    const int xs = bid & 3;
    const int yc = (bid >> 2) & 31;
    const int b  = bid >> 7;
    const int x0 = xs * STRIP;
    const int y0 = yc * YCHUNK;
    const int tid = threadIdx.x;

    // ---- prologue: stage input rows y0-1, y0, y0+1 into ring slots 0,1,2
    for (int r = 0; r < 3; ++r) {
        int row = y0 - 1 + r;
        bool rok = (unsigned)row < HH;
        #pragma unroll
        for (int it = 0; it < 9; ++it) {
            int i = tid + it * 256;
            if (i < NCOL * 16) {
                int col = i >> 4, c4 = i & 15;
                int xx = x0 - 1 + col;
                float4 v = make_float4(0.f, 0.f, 0.f, 0.f);
                if (rok && (unsigned)xx < WW)
                    v = *reinterpret_cast<const float4*>(
                        &dense[(((size_t)b * HH + row) * WW + xx) * CIN + (c4 << 2)]);
                bf16x4 sv = {(__bf16)v.x, (__bf16)v.y, (__bf16)v.z, (__bf16)v.w};
                *reinterpret_cast<bf16x4*>(&patch[(r * NCOL + col) * CPAD + (c4 << 2)]) = sv;
            }
        }
    }
    __syncthreads();

    const int wave = tid >> 6;
    const int lane = tid & 63;
    const int lhi = lane >> 4;   // 0..3
    const int llo = lane & 15;
    const int site_base = (wave & 1) * 64;
    const int co_base   = (wave >> 1) * 64;

    for (int s = 0; s < YCHUNK; ++s) {
        const int y = y0 + s;

        // -- issue staging loads for input row y+2 (T14: load early)
        const int srow = y + 2;
        const bool do_stage = (srow <= y0 + YCHUNK);
        float4 st[9];
        #pragma unroll
        for (int it = 0; it < 9; ++it) {
            st[it] = make_float4(0.f, 0.f, 0.f, 0.f);
            int i = tid + it * 256;
            int col = i >> 4, c4 = i & 15;
            int xx = x0 - 1 + col;
            if (do_stage && i < NCOL * 16 && srow < HH && (unsigned)xx < WW)
                st[it] = *reinterpret_cast<const float4*>(
                    &dense[(((size_t)b * HH + srow) * WW + xx) * CIN + (c4 << 2)]);
        }

        // -- MFMA for output row y (reads ring slots s, s+1, s+2)
        const __bf16* rb[3] = {
            &patch[((s + 0) & 3) * (NCOL * CPAD)],
            &patch[((s + 1) & 3) * (NCOL * CPAD)],
            &patch[((s + 2) & 3) * (NCOL * CPAD)]
        };

        f32x4 acc[4][4];
        #pragma unroll
        for (int mt = 0; mt < 4; ++mt)
            #pragma unroll
            for (int nt = 0; nt < 4; ++nt)
                acc[mt][nt] = (f32x4){0.f, 0.f, 0.f, 0.f};

        #pragma unroll
        for (int off = 0; off < 9; ++off) {
            const int ky = off / 3;
            const int kx = off - ky * 3;
            const __bf16* prow = rb[ky];
            #pragma unroll
            for (int ch = 0; ch < 2; ++ch) {
                bf16x8 a[4];  // A = patch, M = sites
                #pragma unroll
                for (int mt = 0; mt < 4; ++mt)
                    a[mt] = *reinterpret_cast<const bf16x8*>(
                        &prow[(site_base + mt * 16 + llo + kx) * CPAD + ch * 32 + lhi * 8]);
                const __bf16* bbase = wt2 + (size_t)(off * 8 + ch * 4 + lhi) * (COUT * 8);
                #pragma unroll
                for (int nt = 0; nt < 4; ++nt) {
                    bf16x8 bw = *reinterpret_cast<const bf16x8*>(
                        &bbase[(co_base + nt * 16 + llo) * 8]);   // B = weights, N = co
                    #pragma unroll
                    for (int mt = 0; mt < 4; ++mt)
                        acc[mt][nt] = __builtin_amdgcn_mfma_f32_16x16x32_bf16(
                            a[mt], bw, acc[mt][nt], 0, 0, 0);
                }
            }
        }

        // -- write staged row into ring slot (s+3)&3 (T14: write late)
        if (do_stage) {
            __bf16* wslot = &patch[((s + 3) & 3) * (NCOL * CPAD)];
            #pragma unroll
            for (int it = 0; it < 9; ++it) {
                int i = tid + it * 256;
                if (i < NCOL * 16) {
                    int col = i >> 4, c4 = i & 15;
                    bf16x4 sv = {(__bf16)st[it].x, (__bf16)st[it].y,
                                 (__bf16)st[it].z, (__bf16)st[it].w};
                    *reinterpret_cast<bf16x4*>(&wslot[col * CPAD + (c4 << 2)]) = sv;
                }
            }
        }
        __syncthreads();

        // -- store output row y (after barrier: its vmcnt never blocks the ring)
        // D mapping: row = site = lhi*4 + r (consecutive x -> float4), col = co = llo
        #pragma unroll
        for (int nt = 0; nt < 4; ++nt) {
            int co = co_base + nt * 16 + llo;
            float* orow = out + (((size_t)(b * COUT + co) * HH + y) * WW)
                              + x0 + site_base + lhi * 4;
            #pragma unroll
            for (int mt = 0; mt < 4; ++mt)
                *reinterpret_cast<float4*>(&orow[mt * 16]) =
                    *reinterpret_cast<const float4*>(&acc[mt][nt]);
        }
    }
}

extern "C" void kernel_launch(void* const* d_in, const int* in_sizes, int n_in,
                              void* d_out, int out_size, void* d_ws, size_t ws_size,
                              hipStream_t stream) {
    const float* feat  = (const float*)d_in[0];
    const int*   coors = (const int*)d_in[1];
    const float* w     = (const float*)d_in[3];
    float* out = (float*)d_out;

    float* dense = (float*)d_ws;
    const size_t dense_bytes = (size_t)NB * HH * WW * CIN * sizeof(float); // 256 MB
    unsigned short* wt2 = (unsigned short*)((char*)d_ws + dense_bytes);

    const int npts = in_sizes[0] / CIN; // 200000

    const long n4 = (long)NB * HH * WW * CIN / 4;
    hipLaunchKernelGGL(zero_kernel, dim3(2048), dim3(256), 0, stream,
                       (float4*)dense, n4);
    hipLaunchKernelGGL(wt_transform, dim3((COUT * 576 + 255) / 256), dim3(256), 0, stream,
                       w, wt2);
    hipLaunchKernelGGL(scatter_kernel, dim3((npts * 64 + 255) / 256), dim3(256), 0, stream,
                       feat, coors, dense, npts);
    hipLaunchKernelGGL(conv_kernel, dim3(NB * (WW / STRIP) * (HH / YCHUNK)), dim3(256), 0, stream,
                       dense, (const __bf16*)wt2, out);
}